// Round 9
// baseline (528.595 us; speedup 1.0000x reference)
//
#include <hip/hip_runtime.h>

// 32 chained bottleneck blocks on x[16,256,64,64] fp32.
// Phase A: h1_0 = relu(W1_0 x + b1_0)           (reads x once)
// Phase B (x32): h2_k = relu(conv3x3 h1_k), store h2_k;
//                h1_{k+1} = relu(W1_{k+1} relu(W3_k h2_k + b3_k) + b1_{k+1})
// Phase C: out = sum_k relu(W3_k h2_k + b3_k)   (R0 version, 99.5us proven)
//
// R15: R8 proved launch overhead ~0 (fusion: 16x21.5 == 32x10.8 == 344us).
// A step is LDS-INSTRUCTION-bound: ~160 ds-inst/wave (64 broadcast weight
// reads in expand + conv tile + comb). Fix: expand with lane=pixel and
// wave-uniform 64-ch slice -> weights via s_load (SMEM/K$, shared across
// waves), h2 + partial in regs; ds-inst/wave -> ~37. Conv stays on LDS
// tile (R3/R4's global-conv+border-branch was the confound). unroll 4
// bounds in-flight SGPR loads. VGPR ~40 fits (256,4)'s 64-cap -> 16
// waves/CU. 3 barriers.

#define NN 16
#define HH 64
#define WW 64
#define CIN 256
#define CB 4
#define NBLK 32
#define PXT 32  // pixels per phaseC block

// ---------------- Phase A: h1_0 = relu(W1_0 . x + b1_0) ------------------
__global__ __launch_bounds__(256) void phaseA(
    const float* __restrict__ x, const float* __restrict__ w1,
    const float* __restrict__ b1, float* __restrict__ h1out) {
  __shared__ float4 w1s[CIN];
  __shared__ float4 part[4][WW];
  int tid = threadIdx.x;
  for (int i = tid; i < CIN * CB; i += 256) {
    int o = i >> 8, c = i & 255;
    ((float*)&w1s[c])[o] = w1[i]; // w1 global layout [o][c]
  }
  __syncthreads();
  int y = blockIdx.x, n = blockIdx.y;
  int chunk = tid >> 6, px = tid & 63;
  int cbase = chunk * 64;
  const float* xp = x + ((n * CIN + cbase) * HH + y) * WW + px;
  float s0 = 0.f, s1 = 0.f, s2 = 0.f, s3 = 0.f;
#pragma unroll 8
  for (int i = 0; i < 64; ++i) {
    float xv = xp[i * HH * WW];
    float4 wv = w1s[cbase + i];
    s0 = fmaf(xv, wv.x, s0);
    s1 = fmaf(xv, wv.y, s1);
    s2 = fmaf(xv, wv.z, s2);
    s3 = fmaf(xv, wv.w, s3);
  }
  part[chunk][px] = make_float4(s0, s1, s2, s3);
  __syncthreads();
  int px2 = tid >> 2, o = tid & 3;
  float v = ((float*)&part[0][px2])[o] + ((float*)&part[1][px2])[o] +
            ((float*)&part[2][px2])[o] + ((float*)&part[3][px2])[o];
  v += b1[o];
  h1out[((n * HH + y) * WW + px2) * CB + o] = fmaxf(v, 0.f);
}

// ---------------- Phase B: one bottleneck step (hybrid) ------------------
// 8x8 tile, 256 threads, grid (8,8,16) = 1024 blocks = 4/CU, 16 waves/CU.
// Conv: oc = wave, lane = pixel, LDS-staged zero-halo tile.
// Expand+reduce: wave wv owns uniform ch slice [64wv,64wv+64): weights via
// s_load (K$), h2 + 4-float partial in regs. 3 barriers, ~37 ds-inst/wave.
__global__ __launch_bounds__(256, 4) void phaseB(
    const float* __restrict__ h1in, float* __restrict__ h1out,
    float* __restrict__ h2out,
    const float* __restrict__ w2k,   // w2 + k*144, [oc][ic][3][3]
    const float* __restrict__ b2k,   // b2 + k*4
    const float* __restrict__ w3k,   // w3 + k*1024, [c][j]
    const float* __restrict__ b3k,   // b3 + k*256
    const float* __restrict__ w1n,   // w1 + kn*1024, [o][c]
    const float* __restrict__ b1n,   // b1 + kn*4
    int compute_next) {
  __shared__ float4 h1t[10][11];  // zero-halo input tile      1760 B
  __shared__ float h2sb[4][65];   // conv out, +1 pad          1040 B
  __shared__ float4 comb[4][66];  // per-wave partials         4224 B
  int tid = threadIdx.x;
  int lane = tid & 63;
  int wvu = __builtin_amdgcn_readfirstlane(tid >> 6);
  int x0 = blockIdx.x * 8, y0 = blockIdx.y * 8, n = blockIdx.z;
  int lx = lane & 7, ly = lane >> 3;
  int gy = y0 + ly, gx = x0 + lx;

  // ---- stage h1 tile with zero halo (10x10) ----
  if (tid < 100) {
    int cy = tid / 10, cx = tid % 10;
    int sy = y0 + cy - 1, sx = x0 + cx - 1;
    float4 v = make_float4(0.f, 0.f, 0.f, 0.f);
    if (sy >= 0 && sy < HH && sx >= 0 && sx < WW)
      v = *(const float4*)&h1in[((n * HH + sy) * WW + sx) * CB];
    h1t[cy][cx] = v;
  }
  __syncthreads(); // S0

  // ---- conv 3x3 (4->4) + bias + relu: oc = wave, px = lane ----
  {
    const float* w2w = w2k + wvu * 36; // uniform -> s_load (tiny, K$-hot)
    float a0 = b2k[wvu], a1 = 0.f, a2 = 0.f;
#pragma unroll
    for (int dy = 0; dy < 3; ++dy) {
      float4 va = h1t[ly + dy][lx];
      float4 vb = h1t[ly + dy][lx + 1];
      float4 vc = h1t[ly + dy][lx + 2];
      int p = dy * 3;
      a0 = fmaf(va.x, w2w[p], a0);
      a0 = fmaf(va.y, w2w[9 + p], a0);
      a0 = fmaf(va.z, w2w[18 + p], a0);
      a0 = fmaf(va.w, w2w[27 + p], a0);
      a1 = fmaf(vb.x, w2w[p + 1], a1);
      a1 = fmaf(vb.y, w2w[9 + p + 1], a1);
      a1 = fmaf(vb.z, w2w[18 + p + 1], a1);
      a1 = fmaf(vb.w, w2w[27 + p + 1], a1);
      a2 = fmaf(vc.x, w2w[p + 2], a2);
      a2 = fmaf(vc.y, w2w[9 + p + 2], a2);
      a2 = fmaf(vc.z, w2w[18 + p + 2], a2);
      a2 = fmaf(vc.w, w2w[27 + p + 2], a2);
    }
    h2sb[wvu][lane] = fmaxf(a0 + a1 + a2, 0.f);
  }
  __syncthreads(); // S1

  // ---- gather own pixel's 4 channels (2 lanes/bank: free) ----
  float4 h;
  h.x = h2sb[0][lane];
  h.y = h2sb[1][lane];
  h.z = h2sb[2][lane];
  h.w = h2sb[3][lane];
  if (tid < 64) // coalesced float4 h2 store for phaseC
    *(float4*)&h2out[((n * HH + gy) * WW + gx) * CB] = h;

  if (!compute_next) return; // block-uniform: safe before barriers

  // ---- fused expand(W3)+relu+reduce(W1_next): 64 uniform ch per wave ----
  // All weight addresses wave-uniform -> s_load through K$ (shared by all
  // waves on the CU); zero LDS traffic in this loop.
  float4 tp = make_float4(0.f, 0.f, 0.f, 0.f);
  const float* w3r = w3k + wvu * 256;        // [cc][4]
  const float* b3r = b3k + wvu * 64;
  const float* w1r0 = w1n + 0 * 256 + wvu * 64;
  const float* w1r1 = w1n + 1 * 256 + wvu * 64;
  const float* w1r2 = w1n + 2 * 256 + wvu * 64;
  const float* w1r3 = w1n + 3 * 256 + wvu * 64;
#pragma unroll 4  // bound in-flight s_load results (~72 SGPR), allow prefetch
  for (int cc = 0; cc < 64; ++cc) {
    float u = b3r[cc];
    u = fmaf(h.x, w3r[cc * 4 + 0], u);
    u = fmaf(h.y, w3r[cc * 4 + 1], u);
    u = fmaf(h.z, w3r[cc * 4 + 2], u);
    u = fmaf(h.w, w3r[cc * 4 + 3], u);
    float v = fmaxf(u, 0.f);
    tp.x = fmaf(v, w1r0[cc], tp.x);
    tp.y = fmaf(v, w1r1[cc], tp.y);
    tp.z = fmaf(v, w1r2[cc], tp.z);
    tp.w = fmaf(v, w1r3[cc], tp.w);
  }
  comb[wvu][lane] = tp;
  __syncthreads(); // S2

  if (tid < 64) {
    float4 t0 = comb[0][lane], t1 = comb[1][lane];
    float4 t2 = comb[2][lane], t3 = comb[3][lane];
    float4 r;
    r.x = fmaxf(t0.x + t1.x + t2.x + t3.x + b1n[0], 0.f);
    r.y = fmaxf(t0.y + t1.y + t2.y + t3.y + b1n[1], 0.f);
    r.z = fmaxf(t0.z + t1.z + t2.z + t3.z + b1n[2], 0.f);
    r.w = fmaxf(t0.w + t1.w + t2.w + t3.w + b1n[3], 0.f);
    *(float4*)&h1out[((n * HH + gy) * WW + gx) * CB] = r;
  }
}

// ---------------- Phase C: acc = sum_k relu(W3_k h2_k + b3_k) ------------
// R0 version VERBATIM (measured 99-100us, VGPR 52 < 64-cap, 0 conflicts).
__global__ __launch_bounds__(256, 4) void phaseC(
    const float* __restrict__ h2buf, const float* __restrict__ w3g,
    const float* __restrict__ b3g, float* __restrict__ out) {
  __shared__ float4 h2s[2][PXT];
  __shared__ float tr[CIN][PXT + 1]; // +1 pad: 2-way bank alias = free
  int tid = threadIdx.x;             // channel c
  int p0 = blockIdx.x * PXT;         // flat pixel y*64+x
  int n = blockIdx.y;
  float acc[PXT];
#pragma unroll
  for (int i = 0; i < PXT; ++i) acc[i] = 0.f;

  if (tid < PXT)
    h2s[0][tid] = *(const float4*)&h2buf[((0 * NN + n) * 4096 + p0 + tid) * 4];
  __syncthreads();

  for (int k = 0; k < NBLK; ++k) {
    float4 wv = *(const float4*)&w3g[(k * 256 + tid) * 4]; // coalesced
    float bv = b3g[k * 256 + tid];
    if (k + 1 < NBLK && tid < PXT)
      h2s[(k + 1) & 1][tid] =
          *(const float4*)&h2buf[(((k + 1) * NN + n) * 4096 + p0 + tid) * 4];
    const float4* hb = h2s[k & 1];
#pragma unroll
    for (int i = 0; i < PXT; ++i) {
      float4 h = hb[i]; // broadcast ds_read_b128
      float u = fmaf(h.w, wv.w,
                fmaf(h.z, wv.z, fmaf(h.y, wv.y, fmaf(h.x, wv.x, bv))));
      acc[i] += fmaxf(u, 0.f);
    }
    __syncthreads();
  }

  // transpose in LDS -> coalesced stores
#pragma unroll
  for (int i = 0; i < PXT; ++i) tr[tid][i] = acc[i];
  __syncthreads();
  int xi = tid & 31, cb = tid >> 5; // 8 channel-groups per pass
#pragma unroll
  for (int j = 0; j < 32; ++j) {
    int c = cb + j * 8;
    out[(n * CIN + c) * (HH * WW) + p0 + xi] = tr[c][xi];
  }
}

extern "C" void kernel_launch(void* const* d_in, const int* in_sizes, int n_in,
                              void* d_out, int out_size, void* d_ws, size_t ws_size,
                              hipStream_t stream) {
  const float* x  = (const float*)d_in[0];
  const float* w1 = (const float*)d_in[1]; // [32][4][256]
  const float* b1 = (const float*)d_in[2]; // [32][4]
  const float* w2 = (const float*)d_in[3]; // [32][4][4][3][3]
  const float* b2 = (const float*)d_in[4]; // [32][4]
  const float* w3 = (const float*)d_in[5]; // [32][256][4]
  const float* b3 = (const float*)d_in[6]; // [32][256]
  float* out = (float*)d_out;
  float* ws = (float*)d_ws;

  const int STATE = NN * HH * WW * CB; // 262144 floats = 1 MiB
  float* h1a = ws;
  float* h1b = ws + STATE;
  float* h2  = ws + 2 * STATE; // 32 MiB -> total 34 MiB (proven footprint)

  phaseA<<<dim3(HH, NN), 256, 0, stream>>>(x, w1, b1, h1a);
  for (int k = 0; k < NBLK; ++k) {
    const float* hin = (k & 1) ? h1b : h1a;
    float* hout = (k & 1) ? h1a : h1b;
    int kn = (k < NBLK - 1) ? k + 1 : NBLK - 1; // wrapped, unused on last
    phaseB<<<dim3(8, 8, NN), 256, 0, stream>>>(
        hin, hout, h2 + k * STATE,
        w2 + k * 144, b2 + k * CB, w3 + k * 1024, b3 + k * 256,
        w1 + kn * 1024, b1 + kn * CB, (k < NBLK - 1) ? 1 : 0);
  }
  phaseC<<<dim3((HH * WW) / PXT, NN), 256, 0, stream>>>(h2, w3, b3, out);
}

// Round 11
// 468.897 us; speedup vs baseline: 1.1273x; 1.1273x over previous
//
#include <hip/hip_runtime.h>

// 32 chained bottleneck blocks on x[16,256,64,64] fp32.
// Phase A: h1_0 = relu(W1_0 x + b1_0)           (reads x once)
// Phase B2 (x16): TWO fused bottleneck steps per dispatch via halo
//   recompute: stage h1 12x12 (2-halo), step A on 10x10, step B on 8x8.
//   (R8 verbatim: 21.5us/dispatch, best measured; all structural
//   alternatives refuted R1/R4/R8/R9.)
// Phase C: out = sum_k relu(W3_k h2_k + b3_k)
//
// R17 = R16 resubmitted verbatim: R10's run died to "container failed
// twice" (infra; no counters, no test output). Kernel audit found no
// in-kernel cause: workspace layout byte-identical to R8's passing run,
// phaseA/phaseB2 verbatim from R8, phaseC indices bounded by construction.
// R16 theory (still untested): phaseC's 32 per-k barriers + 1-deep weight
// buffering expose latency; 8-slot h2 buffer (barrier per 4 k) + one-k-
// ahead register weight prefetch recovers it. VGPR 52->~58 (< 64 cap);
// LDS 37.9KB -> 4 blocks/CU kept.

#define NN 16
#define HH 64
#define WW 64
#define CIN 256
#define CB 4
#define NBLK 32
#define PXT 32  // pixels per phaseC block

// bijective swizzle: spreads stride-4/2 f4 patterns across banks
__device__ __forceinline__ int swzp(int p) { return p ^ ((p >> 3) & 7); }

// ---------------- Phase A: h1_0 = relu(W1_0 . x + b1_0) ------------------
__global__ __launch_bounds__(256) void phaseA(
    const float* __restrict__ x, const float* __restrict__ w1,
    const float* __restrict__ b1, float* __restrict__ h1out) {
  __shared__ float4 w1s[CIN];
  __shared__ float4 part[4][WW];
  int tid = threadIdx.x;
  for (int i = tid; i < CIN * CB; i += 256) {
    int o = i >> 8, c = i & 255;
    ((float*)&w1s[c])[o] = w1[i]; // w1 global layout [o][c]
  }
  __syncthreads();
  int y = blockIdx.x, n = blockIdx.y;
  int chunk = tid >> 6, px = tid & 63;
  int cbase = chunk * 64;
  const float* xp = x + ((n * CIN + cbase) * HH + y) * WW + px;
  float s0 = 0.f, s1 = 0.f, s2 = 0.f, s3 = 0.f;
#pragma unroll 8
  for (int i = 0; i < 64; ++i) {
    float xv = xp[i * HH * WW];
    float4 wv = w1s[cbase + i];
    s0 = fmaf(xv, wv.x, s0);
    s1 = fmaf(xv, wv.y, s1);
    s2 = fmaf(xv, wv.z, s2);
    s3 = fmaf(xv, wv.w, s3);
  }
  part[chunk][px] = make_float4(s0, s1, s2, s3);
  __syncthreads();
  int px2 = tid >> 2, o = tid & 3;
  float v = ((float*)&part[0][px2])[o] + ((float*)&part[1][px2])[o] +
            ((float*)&part[2][px2])[o] + ((float*)&part[3][px2])[o];
  v += b1[o];
  h1out[((n * HH + y) * WW + px2) * CB + o] = fmaxf(v, 0.f);
}

// ---------------- Phase B2: two fused bottleneck steps (R8 verbatim) -----
__global__ __launch_bounds__(256, 2) void phaseB2(
    const float* __restrict__ h1in, float* __restrict__ h1out,
    float* __restrict__ h2outA, float* __restrict__ h2outB,
    const float* __restrict__ w2A, const float* __restrict__ b2A,
    const float* __restrict__ w3A, const float* __restrict__ b3A,
    const float* __restrict__ w1A, const float* __restrict__ b1A, // k+1
    const float* __restrict__ w2B, const float* __restrict__ b2B,
    const float* __restrict__ w3B, const float* __restrict__ b3B,
    const float* __restrict__ w1B, const float* __restrict__ b1B, // k+2
    int compute_next) {
  __shared__ float4 h1t[12][13];  // staged h1, 2-halo          2496 B
  __shared__ float4 wpk[CIN][2];  // [c][0]=w3, [c][1]=w1next^T 8192 B
  __shared__ float4 b3s[64];      //                            1024 B
  __shared__ float h2A[4][112];   // step-A conv out, 10x10     1792 B
  __shared__ float4 h1n[12][13];  // h1_{k+1} region 10x10      2496 B
  __shared__ float h2Bs[4][64];   // step-B conv out            1024 B
  __shared__ float4 comb[8][117]; // expand partials           14976 B

  int tid = threadIdx.x;
  int lane = tid & 63;
  int wvu = __builtin_amdgcn_readfirstlane(tid >> 6); // conv oc
  int q = tid >> 5, pg = tid & 31;                    // expand split
  int x0 = blockIdx.x * 8, y0 = blockIdx.y * 8, n = blockIdx.z;
  int lx = lane & 7, ly = lane >> 3;

  // ---- P0: stage h1 tile (zero halo) + step-A weights ----
  if (tid < 144) {
    int cy = tid / 12, cx = tid % 12;
    int sy = y0 - 2 + cy, sx = x0 - 2 + cx;
    float4 v = make_float4(0.f, 0.f, 0.f, 0.f);
    if (sy >= 0 && sy < HH && sx >= 0 && sx < WW)
      v = *(const float4*)&h1in[((n * HH + sy) * WW + sx) * CB];
    h1t[cy][cx] = v;
  }
  {
    int c = tid;
    wpk[c][0] = *(const float4*)&w3A[c * 4];
    float4 wt;
    wt.x = w1A[c]; wt.y = w1A[256 + c];
    wt.z = w1A[512 + c]; wt.w = w1A[768 + c];
    wpk[c][1] = wt;
    if (tid < 64) b3s[tid] = *(const float4*)&b3A[tid * 4];
  }
  __syncthreads(); // S0

  // ---- P1: conv A on 10x10 region (oc = wave, <=2 px per lane) ----
  {
    const float* w2w = w2A + wvu * 36; // uniform -> s_load
#pragma unroll
    for (int rep = 0; rep < 2; ++rep) {
      int p = lane + rep * 64;
      if (p < 100) {
        int ay = p / 10, ax = p % 10;
        float a0 = b2A[wvu], a1 = 0.f, a2 = 0.f;
#pragma unroll
        for (int dy = 0; dy < 3; ++dy) {
          float4 va = h1t[ay + dy][ax];
          float4 vb = h1t[ay + dy][ax + 1];
          float4 vc = h1t[ay + dy][ax + 2];
          int pp = dy * 3;
          a0 = fmaf(va.x, w2w[pp], a0);
          a0 = fmaf(va.y, w2w[9 + pp], a0);
          a0 = fmaf(va.z, w2w[18 + pp], a0);
          a0 = fmaf(va.w, w2w[27 + pp], a0);
          a1 = fmaf(vb.x, w2w[pp + 1], a1);
          a1 = fmaf(vb.y, w2w[9 + pp + 1], a1);
          a1 = fmaf(vb.z, w2w[18 + pp + 1], a1);
          a1 = fmaf(vb.w, w2w[27 + pp + 1], a1);
          a2 = fmaf(vc.x, w2w[pp + 2], a2);
          a2 = fmaf(vc.y, w2w[9 + pp + 2], a2);
          a2 = fmaf(vc.z, w2w[18 + pp + 2], a2);
          a2 = fmaf(vc.w, w2w[27 + pp + 2], a2);
        }
        h2A[wvu][p] = fmaxf(a0 + a1 + a2, 0.f);
      }
    }
  }
  __syncthreads(); // S1

  // ---- P2: expand A (32ch x 4px per thread) + h2A interior store ----
  {
    float4 h2r[4], tp[4];
#pragma unroll
    for (int j = 0; j < 4; ++j) {
      int p = pg * 4 + j;
      int pc = (p < 100) ? p : 99;
      h2r[j].x = h2A[0][pc]; h2r[j].y = h2A[1][pc];
      h2r[j].z = h2A[2][pc]; h2r[j].w = h2A[3][pc];
      tp[j] = make_float4(0.f, 0.f, 0.f, 0.f);
    }
#pragma unroll 4  // bound hoisted ds_read results: ~8 f4 in flight max
    for (int cc = 0; cc < 32; ++cc) {
      int c = q * 32 + cc;
      float4 w3v = wpk[c][0]; // 2-addr broadcast per wave
      float4 wnv = wpk[c][1];
      float bb = ((const float*)b3s)[c];
#pragma unroll
      for (int j = 0; j < 4; ++j) {
        float u = fmaf(h2r[j].x, w3v.x, bb);
        u = fmaf(h2r[j].y, w3v.y, u);
        u = fmaf(h2r[j].z, w3v.z, u);
        u = fmaf(h2r[j].w, w3v.w, u);
        float v = fmaxf(u, 0.f);
        tp[j].x = fmaf(v, wnv.x, tp[j].x);
        tp[j].y = fmaf(v, wnv.y, tp[j].y);
        tp[j].z = fmaf(v, wnv.z, tp[j].z);
        tp[j].w = fmaf(v, wnv.w, tp[j].w);
      }
    }
#pragma unroll
    for (int j = 0; j < 4; ++j) {
      int p = pg * 4 + j;
      if (p < 100) comb[q][swzp(p)] = tp[j];
    }
    if (tid < 64) { // gather interior h2A -> global (phaseC input, step kA)
      int p = (ly + 1) * 10 + lx + 1;
      float4 h;
      h.x = h2A[0][p]; h.y = h2A[1][p]; h.z = h2A[2][p]; h.w = h2A[3][p];
      *(float4*)&h2outA[((n * HH + y0 + ly) * WW + x0 + lx) * CB] = h;
    }
  }
  __syncthreads(); // S2

  // ---- P3: reduce A -> h1n (10x10, zero outside image) + stage B wts ----
  if (tid < 100) {
    int m = swzp(tid);
    float4 t = comb[0][m];
#pragma unroll 4  // limit hoisted comb reads
    for (int qq = 1; qq < 8; ++qq) {
      float4 pv = comb[qq][m];
      t.x += pv.x; t.y += pv.y; t.z += pv.z; t.w += pv.w;
    }
    int ay = tid / 10, ax = tid % 10;
    int gy = y0 - 1 + ay, gx = x0 - 1 + ax;
    float4 r;
    r.x = fmaxf(t.x + b1A[0], 0.f);
    r.y = fmaxf(t.y + b1A[1], 0.f);
    r.z = fmaxf(t.z + b1A[2], 0.f);
    r.w = fmaxf(t.w + b1A[3], 0.f);
    if (gy < 0 || gy >= HH || gx < 0 || gx >= WW)
      r = make_float4(0.f, 0.f, 0.f, 0.f); // exact SAME-pad for step B
    h1n[ay][ax] = r;
  }
  {
    int c = tid;
    wpk[c][0] = *(const float4*)&w3B[c * 4];
    float4 wt;
    wt.x = w1B[c]; wt.y = w1B[256 + c];
    wt.z = w1B[512 + c]; wt.w = w1B[768 + c];
    wpk[c][1] = wt;
    if (tid < 64) b3s[tid] = *(const float4*)&b3B[tid * 4];
  }
  __syncthreads(); // S3

  // ---- P4: conv B on 8x8 tile (oc = wave, 1 px per lane) ----
  {
    const float* w2w = w2B + wvu * 36; // uniform -> s_load
    float a0 = b2B[wvu], a1 = 0.f, a2 = 0.f;
#pragma unroll
    for (int dy = 0; dy < 3; ++dy) {
      float4 va = h1n[ly + dy][lx];
      float4 vb = h1n[ly + dy][lx + 1];
      float4 vc = h1n[ly + dy][lx + 2];
      int pp = dy * 3;
      a0 = fmaf(va.x, w2w[pp], a0);
      a0 = fmaf(va.y, w2w[9 + pp], a0);
      a0 = fmaf(va.z, w2w[18 + pp], a0);
      a0 = fmaf(va.w, w2w[27 + pp], a0);
      a1 = fmaf(vb.x, w2w[pp + 1], a1);
      a1 = fmaf(vb.y, w2w[9 + pp + 1], a1);
      a1 = fmaf(vb.z, w2w[18 + pp + 1], a1);
      a1 = fmaf(vb.w, w2w[27 + pp + 1], a1);
      a2 = fmaf(vc.x, w2w[pp + 2], a2);
      a2 = fmaf(vc.y, w2w[9 + pp + 2], a2);
      a2 = fmaf(vc.z, w2w[18 + pp + 2], a2);
      a2 = fmaf(vc.w, w2w[27 + pp + 2], a2);
    }
    h2Bs[wvu][lane] = fmaxf(a0 + a1 + a2, 0.f);
  }
  __syncthreads(); // S4

  // ---- P5: h2B store + expand B (32ch x 2px per thread) ----
  if (tid < 64) {
    float4 h;
    h.x = h2Bs[0][lane]; h.y = h2Bs[1][lane];
    h.z = h2Bs[2][lane]; h.w = h2Bs[3][lane];
    *(float4*)&h2outB[((n * HH + y0 + ly) * WW + x0 + lx) * CB] = h;
  }
  if (compute_next) {
    float4 hb[2], tp[2];
#pragma unroll
    for (int j = 0; j < 2; ++j) {
      int p = pg * 2 + j;
      hb[j].x = h2Bs[0][p]; hb[j].y = h2Bs[1][p];
      hb[j].z = h2Bs[2][p]; hb[j].w = h2Bs[3][p];
      tp[j] = make_float4(0.f, 0.f, 0.f, 0.f);
    }
#pragma unroll 4  // bound hoisted ds_read results
    for (int cc = 0; cc < 32; ++cc) {
      int c = q * 32 + cc;
      float4 w3v = wpk[c][0];
      float4 wnv = wpk[c][1];
      float bb = ((const float*)b3s)[c];
#pragma unroll
      for (int j = 0; j < 2; ++j) {
        float u = fmaf(hb[j].x, w3v.x, bb);
        u = fmaf(hb[j].y, w3v.y, u);
        u = fmaf(hb[j].z, w3v.z, u);
        u = fmaf(hb[j].w, w3v.w, u);
        float v = fmaxf(u, 0.f);
        tp[j].x = fmaf(v, wnv.x, tp[j].x);
        tp[j].y = fmaf(v, wnv.y, tp[j].y);
        tp[j].z = fmaf(v, wnv.z, tp[j].z);
        tp[j].w = fmaf(v, wnv.w, tp[j].w);
      }
    }
#pragma unroll
    for (int j = 0; j < 2; ++j) comb[q][swzp(pg * 2 + j)] = tp[j];
  }
  __syncthreads(); // S5

  if (compute_next && tid < 64) {
    int m = swzp(lane);
    float4 t = comb[0][m];
#pragma unroll 4  // limit hoisted comb reads
    for (int qq = 1; qq < 8; ++qq) {
      float4 pv = comb[qq][m];
      t.x += pv.x; t.y += pv.y; t.z += pv.z; t.w += pv.w;
    }
    float4 r;
    r.x = fmaxf(t.x + b1B[0], 0.f);
    r.y = fmaxf(t.y + b1B[1], 0.f);
    r.z = fmaxf(t.z + b1B[2], 0.f);
    r.w = fmaxf(t.w + b1B[3], 0.f);
    *(float4*)&h1out[((n * HH + y0 + ly) * WW + x0 + lx) * CB] = r;
  }
}

// ---------------- Phase C: acc = sum_k relu(W3_k h2_k + b3_k) ------------
// R0 compute core + 8-slot h2 buffer (2 groups x 4 k, barrier per 4 k) +
// weight/bias register prefetch one k ahead. Lane = channel, PXT=32 px.
// VGPR ~58 < 64 cap at (256,4); LDS 37.9 KB -> 4 blocks/CU.
__global__ __launch_bounds__(256, 4) void phaseC(
    const float* __restrict__ h2buf, const float* __restrict__ w3g,
    const float* __restrict__ b3g, float* __restrict__ out) {
  __shared__ float4 h2s[8][PXT];     // 2 groups x 4 k          4 KB
  __shared__ float tr[CIN][PXT + 1]; // +1 pad: 2-way alias free
  int tid = threadIdx.x;             // channel c
  int p0 = blockIdx.x * PXT;         // flat pixel y*64+x
  int n = blockIdx.y;
  float acc[PXT];
#pragma unroll
  for (int i = 0; i < PXT; ++i) acc[i] = 0.f;

  // prologue: stage k=0..3 (threads 0-127: slot tid>>5, px tid&31)
  if (tid < 128) {
    int kk = tid >> 5, px = tid & 31;
    h2s[kk][px] =
        *(const float4*)&h2buf[((kk * NN + n) * 4096 + p0 + px) * 4];
  }
  __syncthreads();

  // weight prefetch registers (k=0)
  float4 wv = *(const float4*)&w3g[(0 * 256 + tid) * 4];
  float bv = b3g[0 * 256 + tid];

  for (int g = 0; g < 8; ++g) {
    if (g < 7 && tid < 128) { // stage next group into the other 4 slots
      int kk = tid >> 5, px = tid & 31;
      int k = (g + 1) * 4 + kk;
      h2s[(((g + 1) & 1) << 2) + kk][px] =
          *(const float4*)&h2buf[((k * NN + n) * 4096 + p0 + px) * 4];
    }
#pragma unroll 1  // keep pressure bounded: one k's weights + next in flight
    for (int j = 0; j < 4; ++j) {
      int k = g * 4 + j;
      int knx = (k + 1 < NBLK) ? k + 1 : NBLK - 1; // clamped, unused at end
      float4 wvn = *(const float4*)&w3g[(knx * 256 + tid) * 4];
      float bvn = b3g[knx * 256 + tid];
      const float4* hb = h2s[((g & 1) << 2) + j];
#pragma unroll
      for (int i = 0; i < PXT; ++i) {
        float4 h = hb[i]; // broadcast ds_read_b128
        float u = fmaf(h.w, wv.w,
                  fmaf(h.z, wv.z, fmaf(h.y, wv.y, fmaf(h.x, wv.x, bv))));
        acc[i] += fmaxf(u, 0.f);
      }
      wv = wvn; bv = bvn;
    }
    __syncthreads(); // group consumed; next group staged
  }

  // transpose in LDS -> coalesced stores (R0 verbatim)
#pragma unroll
  for (int i = 0; i < PXT; ++i) tr[tid][i] = acc[i];
  __syncthreads();
  int xi = tid & 31, cb = tid >> 5; // 8 channel-groups per pass
#pragma unroll
  for (int j = 0; j < 32; ++j) {
    int c = cb + j * 8;
    out[(n * CIN + c) * (HH * WW) + p0 + xi] = tr[c][xi];
  }
}

extern "C" void kernel_launch(void* const* d_in, const int* in_sizes, int n_in,
                              void* d_out, int out_size, void* d_ws, size_t ws_size,
                              hipStream_t stream) {
  const float* x  = (const float*)d_in[0];
  const float* w1 = (const float*)d_in[1]; // [32][4][256]
  const float* b1 = (const float*)d_in[2]; // [32][4]
  const float* w2 = (const float*)d_in[3]; // [32][4][4][3][3]
  const float* b2 = (const float*)d_in[4]; // [32][4]
  const float* w3 = (const float*)d_in[5]; // [32][256][4]
  const float* b3 = (const float*)d_in[6]; // [32][256]
  float* out = (float*)d_out;
  float* ws = (float*)d_ws;

  const int STATE = NN * HH * WW * CB; // 262144 floats = 1 MiB
  float* h1a = ws;
  float* h1b = ws + STATE;
  float* h2  = ws + 2 * STATE; // 32 MiB -> total 34 MiB (proven footprint)

  phaseA<<<dim3(HH, NN), 256, 0, stream>>>(x, w1, b1, h1a);
  for (int t = 0; t < NBLK / 2; ++t) {
    int kA = 2 * t, kB = 2 * t + 1;
    const float* hin = (t & 1) ? h1b : h1a;
    float* hout = (t & 1) ? h1a : h1b;
    int knA = kA + 1;                       // always <= 31
    int knB = (kB + 1 < NBLK) ? kB + 1 : NBLK - 1; // clamped, unused on last
    phaseB2<<<dim3(8, 8, NN), 256, 0, stream>>>(
        hin, hout, h2 + kA * STATE, h2 + kB * STATE,
        w2 + kA * 144, b2 + kA * CB, w3 + kA * 1024, b3 + kA * 256,
        w1 + knA * 1024, b1 + knA * CB,
        w2 + kB * 144, b2 + kB * CB, w3 + kB * 1024, b3 + kB * 256,
        w1 + knB * 1024, b1 + knB * CB,
        (t < NBLK / 2 - 1) ? 1 : 0);
  }
  phaseC<<<dim3((HH * WW) / PXT, NN), 256, 0, stream>>>(h2, w3, b3, out);
}

// Round 12
// 466.509 us; speedup vs baseline: 1.1331x; 1.0051x over previous
//
#include <hip/hip_runtime.h>

// 32 chained bottleneck blocks on x[16,256,64,64] fp32.
// Phase A: h1_0 = relu(W1_0 x + b1_0)           (reads x once)
// Phase B2 (x16): TWO fused bottleneck steps per dispatch via halo
//   recompute: stage h1 12x12 (2-halo), step A on 10x10, step B on 8x8.
// Phase C: out = sum_k relu(W3_k h2_k + b3_k)   (R0 version, 99.5us proven)
//
// R18 = R8 resubmitted verbatim (best measured: 458.5us). R11 refuted the
// last open theory (phaseC group-buffer + weight prefetch: 99.5->110us;
// per-iteration load retirement serialized what R0's loop-top load let the
// scheduler overlap). Ledger: phaseB 10.75us/step across 4 structural
// variants (launch overhead ~0, mega-kernel blocked by VGPR caps + broken
// cooperative launch); phaseC R0 beat 3 restructurings; phaseA BW-bound.
// All phases at measured structural floors.

#define NN 16
#define HH 64
#define WW 64
#define CIN 256
#define CB 4
#define NBLK 32
#define PXT 32  // pixels per phaseC block

// bijective swizzle: spreads stride-4/2 f4 patterns across banks
__device__ __forceinline__ int swzp(int p) { return p ^ ((p >> 3) & 7); }

// ---------------- Phase A: h1_0 = relu(W1_0 . x + b1_0) ------------------
__global__ __launch_bounds__(256) void phaseA(
    const float* __restrict__ x, const float* __restrict__ w1,
    const float* __restrict__ b1, float* __restrict__ h1out) {
  __shared__ float4 w1s[CIN];
  __shared__ float4 part[4][WW];
  int tid = threadIdx.x;
  for (int i = tid; i < CIN * CB; i += 256) {
    int o = i >> 8, c = i & 255;
    ((float*)&w1s[c])[o] = w1[i]; // w1 global layout [o][c]
  }
  __syncthreads();
  int y = blockIdx.x, n = blockIdx.y;
  int chunk = tid >> 6, px = tid & 63;
  int cbase = chunk * 64;
  const float* xp = x + ((n * CIN + cbase) * HH + y) * WW + px;
  float s0 = 0.f, s1 = 0.f, s2 = 0.f, s3 = 0.f;
#pragma unroll 8
  for (int i = 0; i < 64; ++i) {
    float xv = xp[i * HH * WW];
    float4 wv = w1s[cbase + i];
    s0 = fmaf(xv, wv.x, s0);
    s1 = fmaf(xv, wv.y, s1);
    s2 = fmaf(xv, wv.z, s2);
    s3 = fmaf(xv, wv.w, s3);
  }
  part[chunk][px] = make_float4(s0, s1, s2, s3);
  __syncthreads();
  int px2 = tid >> 2, o = tid & 3;
  float v = ((float*)&part[0][px2])[o] + ((float*)&part[1][px2])[o] +
            ((float*)&part[2][px2])[o] + ((float*)&part[3][px2])[o];
  v += b1[o];
  h1out[((n * HH + y) * WW + px2) * CB + o] = fmaxf(v, 0.f);
}

// ---------------- Phase B2: two fused bottleneck steps -------------------
// 8x8 output tile, 256 threads, grid (8,8,16) = 1024 blocks.
// Step A on the 10x10 halo region (recompute), step B on the 8x8 tile.
// Expand: q = tid>>5 owns 32 channels (weight reads 2-addr broadcast),
// pg = tid&31 owns 4 px (A) / 2 px (B). 6 barriers per dispatch.
// (256,2): 128-VGPR cap; unroll-4 keeps live set ~100 -> no spill.
__global__ __launch_bounds__(256, 2) void phaseB2(
    const float* __restrict__ h1in, float* __restrict__ h1out,
    float* __restrict__ h2outA, float* __restrict__ h2outB,
    const float* __restrict__ w2A, const float* __restrict__ b2A,
    const float* __restrict__ w3A, const float* __restrict__ b3A,
    const float* __restrict__ w1A, const float* __restrict__ b1A, // k+1
    const float* __restrict__ w2B, const float* __restrict__ b2B,
    const float* __restrict__ w3B, const float* __restrict__ b3B,
    const float* __restrict__ w1B, const float* __restrict__ b1B, // k+2
    int compute_next) {
  __shared__ float4 h1t[12][13];  // staged h1, 2-halo          2496 B
  __shared__ float4 wpk[CIN][2];  // [c][0]=w3, [c][1]=w1next^T 8192 B
  __shared__ float4 b3s[64];      //                            1024 B
  __shared__ float h2A[4][112];   // step-A conv out, 10x10     1792 B
  __shared__ float4 h1n[12][13];  // h1_{k+1} region 10x10      2496 B
  __shared__ float h2Bs[4][64];   // step-B conv out            1024 B
  __shared__ float4 comb[8][117]; // expand partials           14976 B

  int tid = threadIdx.x;
  int lane = tid & 63;
  int wvu = __builtin_amdgcn_readfirstlane(tid >> 6); // conv oc
  int q = tid >> 5, pg = tid & 31;                    // expand split
  int x0 = blockIdx.x * 8, y0 = blockIdx.y * 8, n = blockIdx.z;
  int lx = lane & 7, ly = lane >> 3;

  // ---- P0: stage h1 tile (zero halo) + step-A weights ----
  if (tid < 144) {
    int cy = tid / 12, cx = tid % 12;
    int sy = y0 - 2 + cy, sx = x0 - 2 + cx;
    float4 v = make_float4(0.f, 0.f, 0.f, 0.f);
    if (sy >= 0 && sy < HH && sx >= 0 && sx < WW)
      v = *(const float4*)&h1in[((n * HH + sy) * WW + sx) * CB];
    h1t[cy][cx] = v;
  }
  {
    int c = tid;
    wpk[c][0] = *(const float4*)&w3A[c * 4];
    float4 wt;
    wt.x = w1A[c]; wt.y = w1A[256 + c];
    wt.z = w1A[512 + c]; wt.w = w1A[768 + c];
    wpk[c][1] = wt;
    if (tid < 64) b3s[tid] = *(const float4*)&b3A[tid * 4];
  }
  __syncthreads(); // S0

  // ---- P1: conv A on 10x10 region (oc = wave, <=2 px per lane) ----
  {
    const float* w2w = w2A + wvu * 36; // uniform -> s_load
#pragma unroll
    for (int rep = 0; rep < 2; ++rep) {
      int p = lane + rep * 64;
      if (p < 100) {
        int ay = p / 10, ax = p % 10;
        float a0 = b2A[wvu], a1 = 0.f, a2 = 0.f;
#pragma unroll
        for (int dy = 0; dy < 3; ++dy) {
          float4 va = h1t[ay + dy][ax];
          float4 vb = h1t[ay + dy][ax + 1];
          float4 vc = h1t[ay + dy][ax + 2];
          int pp = dy * 3;
          a0 = fmaf(va.x, w2w[pp], a0);
          a0 = fmaf(va.y, w2w[9 + pp], a0);
          a0 = fmaf(va.z, w2w[18 + pp], a0);
          a0 = fmaf(va.w, w2w[27 + pp], a0);
          a1 = fmaf(vb.x, w2w[pp + 1], a1);
          a1 = fmaf(vb.y, w2w[9 + pp + 1], a1);
          a1 = fmaf(vb.z, w2w[18 + pp + 1], a1);
          a1 = fmaf(vb.w, w2w[27 + pp + 1], a1);
          a2 = fmaf(vc.x, w2w[pp + 2], a2);
          a2 = fmaf(vc.y, w2w[9 + pp + 2], a2);
          a2 = fmaf(vc.z, w2w[18 + pp + 2], a2);
          a2 = fmaf(vc.w, w2w[27 + pp + 2], a2);
        }
        h2A[wvu][p] = fmaxf(a0 + a1 + a2, 0.f);
      }
    }
  }
  __syncthreads(); // S1

  // ---- P2: expand A (32ch x 4px per thread) + h2A interior store ----
  {
    float4 h2r[4], tp[4];
#pragma unroll
    for (int j = 0; j < 4; ++j) {
      int p = pg * 4 + j;
      int pc = (p < 100) ? p : 99;
      h2r[j].x = h2A[0][pc]; h2r[j].y = h2A[1][pc];
      h2r[j].z = h2A[2][pc]; h2r[j].w = h2A[3][pc];
      tp[j] = make_float4(0.f, 0.f, 0.f, 0.f);
    }
#pragma unroll 4  // bound hoisted ds_read results: ~8 f4 in flight max
    for (int cc = 0; cc < 32; ++cc) {
      int c = q * 32 + cc;
      float4 w3v = wpk[c][0]; // 2-addr broadcast per wave
      float4 wnv = wpk[c][1];
      float bb = ((const float*)b3s)[c];
#pragma unroll
      for (int j = 0; j < 4; ++j) {
        float u = fmaf(h2r[j].x, w3v.x, bb);
        u = fmaf(h2r[j].y, w3v.y, u);
        u = fmaf(h2r[j].z, w3v.z, u);
        u = fmaf(h2r[j].w, w3v.w, u);
        float v = fmaxf(u, 0.f);
        tp[j].x = fmaf(v, wnv.x, tp[j].x);
        tp[j].y = fmaf(v, wnv.y, tp[j].y);
        tp[j].z = fmaf(v, wnv.z, tp[j].z);
        tp[j].w = fmaf(v, wnv.w, tp[j].w);
      }
    }
#pragma unroll
    for (int j = 0; j < 4; ++j) {
      int p = pg * 4 + j;
      if (p < 100) comb[q][swzp(p)] = tp[j];
    }
    if (tid < 64) { // gather interior h2A -> global (phaseC input, step kA)
      int p = (ly + 1) * 10 + lx + 1;
      float4 h;
      h.x = h2A[0][p]; h.y = h2A[1][p]; h.z = h2A[2][p]; h.w = h2A[3][p];
      *(float4*)&h2outA[((n * HH + y0 + ly) * WW + x0 + lx) * CB] = h;
    }
  }
  __syncthreads(); // S2

  // ---- P3: reduce A -> h1n (10x10, zero outside image) + stage B wts ----
  if (tid < 100) {
    int m = swzp(tid);
    float4 t = comb[0][m];
#pragma unroll 4  // limit hoisted comb reads
    for (int qq = 1; qq < 8; ++qq) {
      float4 pv = comb[qq][m];
      t.x += pv.x; t.y += pv.y; t.z += pv.z; t.w += pv.w;
    }
    int ay = tid / 10, ax = tid % 10;
    int gy = y0 - 1 + ay, gx = x0 - 1 + ax;
    float4 r;
    r.x = fmaxf(t.x + b1A[0], 0.f);
    r.y = fmaxf(t.y + b1A[1], 0.f);
    r.z = fmaxf(t.z + b1A[2], 0.f);
    r.w = fmaxf(t.w + b1A[3], 0.f);
    if (gy < 0 || gy >= HH || gx < 0 || gx >= WW)
      r = make_float4(0.f, 0.f, 0.f, 0.f); // exact SAME-pad for step B
    h1n[ay][ax] = r;
  }
  {
    int c = tid;
    wpk[c][0] = *(const float4*)&w3B[c * 4];
    float4 wt;
    wt.x = w1B[c]; wt.y = w1B[256 + c];
    wt.z = w1B[512 + c]; wt.w = w1B[768 + c];
    wpk[c][1] = wt;
    if (tid < 64) b3s[tid] = *(const float4*)&b3B[tid * 4];
  }
  __syncthreads(); // S3

  // ---- P4: conv B on 8x8 tile (oc = wave, 1 px per lane) ----
  {
    const float* w2w = w2B + wvu * 36; // uniform -> s_load
    float a0 = b2B[wvu], a1 = 0.f, a2 = 0.f;
#pragma unroll
    for (int dy = 0; dy < 3; ++dy) {
      float4 va = h1n[ly + dy][lx];
      float4 vb = h1n[ly + dy][lx + 1];
      float4 vc = h1n[ly + dy][lx + 2];
      int pp = dy * 3;
      a0 = fmaf(va.x, w2w[pp], a0);
      a0 = fmaf(va.y, w2w[9 + pp], a0);
      a0 = fmaf(va.z, w2w[18 + pp], a0);
      a0 = fmaf(va.w, w2w[27 + pp], a0);
      a1 = fmaf(vb.x, w2w[pp + 1], a1);
      a1 = fmaf(vb.y, w2w[9 + pp + 1], a1);
      a1 = fmaf(vb.z, w2w[18 + pp + 1], a1);
      a1 = fmaf(vb.w, w2w[27 + pp + 1], a1);
      a2 = fmaf(vc.x, w2w[pp + 2], a2);
      a2 = fmaf(vc.y, w2w[9 + pp + 2], a2);
      a2 = fmaf(vc.z, w2w[18 + pp + 2], a2);
      a2 = fmaf(vc.w, w2w[27 + pp + 2], a2);
    }
    h2Bs[wvu][lane] = fmaxf(a0 + a1 + a2, 0.f);
  }
  __syncthreads(); // S4

  // ---- P5: h2B store + expand B (32ch x 2px per thread) ----
  if (tid < 64) {
    float4 h;
    h.x = h2Bs[0][lane]; h.y = h2Bs[1][lane];
    h.z = h2Bs[2][lane]; h.w = h2Bs[3][lane];
    *(float4*)&h2outB[((n * HH + y0 + ly) * WW + x0 + lx) * CB] = h;
  }
  if (compute_next) {
    float4 hb[2], tp[2];
#pragma unroll
    for (int j = 0; j < 2; ++j) {
      int p = pg * 2 + j;
      hb[j].x = h2Bs[0][p]; hb[j].y = h2Bs[1][p];
      hb[j].z = h2Bs[2][p]; hb[j].w = h2Bs[3][p];
      tp[j] = make_float4(0.f, 0.f, 0.f, 0.f);
    }
#pragma unroll 4  // bound hoisted ds_read results
    for (int cc = 0; cc < 32; ++cc) {
      int c = q * 32 + cc;
      float4 w3v = wpk[c][0];
      float4 wnv = wpk[c][1];
      float bb = ((const float*)b3s)[c];
#pragma unroll
      for (int j = 0; j < 2; ++j) {
        float u = fmaf(hb[j].x, w3v.x, bb);
        u = fmaf(hb[j].y, w3v.y, u);
        u = fmaf(hb[j].z, w3v.z, u);
        u = fmaf(hb[j].w, w3v.w, u);
        float v = fmaxf(u, 0.f);
        tp[j].x = fmaf(v, wnv.x, tp[j].x);
        tp[j].y = fmaf(v, wnv.y, tp[j].y);
        tp[j].z = fmaf(v, wnv.z, tp[j].z);
        tp[j].w = fmaf(v, wnv.w, tp[j].w);
      }
    }
#pragma unroll
    for (int j = 0; j < 2; ++j) comb[q][swzp(pg * 2 + j)] = tp[j];
  }
  __syncthreads(); // S5

  if (compute_next && tid < 64) {
    int m = swzp(lane);
    float4 t = comb[0][m];
#pragma unroll 4  // limit hoisted comb reads
    for (int qq = 1; qq < 8; ++qq) {
      float4 pv = comb[qq][m];
      t.x += pv.x; t.y += pv.y; t.z += pv.z; t.w += pv.w;
    }
    float4 r;
    r.x = fmaxf(t.x + b1B[0], 0.f);
    r.y = fmaxf(t.y + b1B[1], 0.f);
    r.z = fmaxf(t.z + b1B[2], 0.f);
    r.w = fmaxf(t.w + b1B[3], 0.f);
    *(float4*)&h1out[((n * HH + y0 + ly) * WW + x0 + lx) * CB] = r;
  }
}

// ---------------- Phase C: acc = sum_k relu(W3_k h2_k + b3_k) ------------
// R0 version VERBATIM (measured 99-100us, VGPR 52 < 64-cap, 0 conflicts).
__global__ __launch_bounds__(256, 4) void phaseC(
    const float* __restrict__ h2buf, const float* __restrict__ w3g,
    const float* __restrict__ b3g, float* __restrict__ out) {
  __shared__ float4 h2s[2][PXT];
  __shared__ float tr[CIN][PXT + 1]; // +1 pad: 2-way bank alias = free
  int tid = threadIdx.x;             // channel c
  int p0 = blockIdx.x * PXT;         // flat pixel y*64+x
  int n = blockIdx.y;
  float acc[PXT];
#pragma unroll
  for (int i = 0; i < PXT; ++i) acc[i] = 0.f;

  if (tid < PXT)
    h2s[0][tid] = *(const float4*)&h2buf[((0 * NN + n) * 4096 + p0 + tid) * 4];
  __syncthreads();

  for (int k = 0; k < NBLK; ++k) {
    float4 wv = *(const float4*)&w3g[(k * 256 + tid) * 4]; // coalesced
    float bv = b3g[k * 256 + tid];
    if (k + 1 < NBLK && tid < PXT)
      h2s[(k + 1) & 1][tid] =
          *(const float4*)&h2buf[(((k + 1) * NN + n) * 4096 + p0 + tid) * 4];
    const float4* hb = h2s[k & 1];
#pragma unroll
    for (int i = 0; i < PXT; ++i) {
      float4 h = hb[i]; // broadcast ds_read_b128
      float u = fmaf(h.w, wv.w,
                fmaf(h.z, wv.z, fmaf(h.y, wv.y, fmaf(h.x, wv.x, bv))));
      acc[i] += fmaxf(u, 0.f);
    }
    __syncthreads();
  }

  // transpose in LDS -> coalesced stores
#pragma unroll
  for (int i = 0; i < PXT; ++i) tr[tid][i] = acc[i];
  __syncthreads();
  int xi = tid & 31, cb = tid >> 5; // 8 channel-groups per pass
#pragma unroll
  for (int j = 0; j < 32; ++j) {
    int c = cb + j * 8;
    out[(n * CIN + c) * (HH * WW) + p0 + xi] = tr[c][xi];
  }
}

extern "C" void kernel_launch(void* const* d_in, const int* in_sizes, int n_in,
                              void* d_out, int out_size, void* d_ws, size_t ws_size,
                              hipStream_t stream) {
  const float* x  = (const float*)d_in[0];
  const float* w1 = (const float*)d_in[1]; // [32][4][256]
  const float* b1 = (const float*)d_in[2]; // [32][4]
  const float* w2 = (const float*)d_in[3]; // [32][4][4][3][3]
  const float* b2 = (const float*)d_in[4]; // [32][4]
  const float* w3 = (const float*)d_in[5]; // [32][256][4]
  const float* b3 = (const float*)d_in[6]; // [32][256]
  float* out = (float*)d_out;
  float* ws = (float*)d_ws;

  const int STATE = NN * HH * WW * CB; // 262144 floats = 1 MiB
  float* h1a = ws;
  float* h1b = ws + STATE;
  float* h2  = ws + 2 * STATE; // 32 MiB -> total 34 MiB (proven footprint)

  phaseA<<<dim3(HH, NN), 256, 0, stream>>>(x, w1, b1, h1a);
  for (int t = 0; t < NBLK / 2; ++t) {
    int kA = 2 * t, kB = 2 * t + 1;
    const float* hin = (t & 1) ? h1b : h1a;
    float* hout = (t & 1) ? h1a : h1b;
    int knA = kA + 1;                       // always <= 31
    int knB = (kB + 1 < NBLK) ? kB + 1 : NBLK - 1; // clamped, unused on last
    phaseB2<<<dim3(8, 8, NN), 256, 0, stream>>>(
        hin, hout, h2 + kA * STATE, h2 + kB * STATE,
        w2 + kA * 144, b2 + kA * CB, w3 + kA * 1024, b3 + kA * 256,
        w1 + knA * 1024, b1 + knA * CB,
        w2 + kB * 144, b2 + kB * CB, w3 + kB * 1024, b3 + kB * 256,
        w1 + knB * 1024, b1 + knB * CB,
        (t < NBLK / 2 - 1) ? 1 : 0);
  }
  phaseC<<<dim3((HH * WW) / PXT, NN), 256, 0, stream>>>(h2, w3, b3, out);
}